// Round 6
// baseline (327.344 us; speedup 1.0000x reference)
//
#include <hip/hip_runtime.h>
#include <hip/hip_fp16.h>

// ---------------------------------------------------------------------------
// Toeplitz/FFT formulation of the density-compensated NUFFT normal operator:
//   out_b = IFFT2_512( That .* FFT2_512( pad(x_b) ) )  cropped to 256x256
// where That = FFT2(tc), tc = circular embedding of
//   t[a,b] = (1/N^2) sum_m d[m] exp(+2pi i (kx[m] a + ky[m] b)),  a,b in [-255,255]
// This is EXACT (pure NDFT normal op is Toeplitz; pixel-center offsets cancel).
// ---------------------------------------------------------------------------

constexpr int IMG = 256;
constexpr int NF  = 512;
constexpr int Mm  = 1920;
constexpr int B_  = 64;
constexpr int BH  = 32;    // batch half processed per pipeline sweep

typedef _Float16 half8 __attribute__((ext_vector_type(8)));
typedef float floatx16 __attribute__((ext_vector_type(16)));

__device__ __forceinline__ void gl_lds16(const void* g, void* l) {
  __builtin_amdgcn_global_load_lds(
      (const __attribute__((address_space(1))) unsigned int*)g,
      (__attribute__((address_space(3))) unsigned int*)l, 16, 0, 0);
}

__device__ __forceinline__ void cmulf(float& r, float& i, float c, float s) {
  float tr = r * c - i * s;
  i = r * s + i * c;
  r = tr;
}

// ---------------------------------------------------------------------------
// Wave-level 512-point complex FFT.
// Data: 8 complex per lane; element n = 64*s + lane (s = reg, natural order).
// Forward output is stored in "slot" order: slot(pos,l) = 64*rev3[pos] + l,
// encoding freq k = rev3[pos] + 8*bitrev6(l). ALL forward passes (rows, cols,
// That build) use the same program, so the elementwise That multiply is done
// directly in slot space; inverse is the exact reversed program.
// ---------------------------------------------------------------------------
#define REV3_INIT const int rev3[8] = {0, 4, 2, 6, 1, 5, 3, 7}

__device__ __forceinline__ void wfft_fwd(float* xr, float* xi, int l) {
  const float C = 0.70710678118654752f;
  // 8-pt DIF over regs --- stage d=4
#pragma unroll
  for (int n = 0; n < 4; ++n) {
    float tr = xr[n] - xr[n + 4], ti = xi[n] - xi[n + 4];
    xr[n] += xr[n + 4]; xi[n] += xi[n + 4];
    xr[n + 4] = tr; xi[n + 4] = ti;
  }
  { float a = xr[5], b = xi[5]; xr[5] = C * (a + b); xi[5] = C * (b - a); }   // *W8^1
  { float a = xr[6], b = xi[6]; xr[6] = b; xi[6] = -a; }                      // *-i
  { float a = xr[7], b = xi[7]; xr[7] = C * (b - a); xi[7] = -C * (a + b); }  // *W8^3
  // stage d=2
#pragma unroll
  for (int h = 0; h < 8; h += 4) {
    { float tr = xr[h] - xr[h + 2], ti = xi[h] - xi[h + 2];
      xr[h] += xr[h + 2]; xi[h] += xi[h + 2];
      xr[h + 2] = tr; xi[h + 2] = ti; }
    { float tr = xr[h + 1] - xr[h + 3], ti = xi[h + 1] - xi[h + 3];
      xr[h + 1] += xr[h + 3]; xi[h + 1] += xi[h + 3];
      xr[h + 3] = ti; xi[h + 3] = -tr; }                                      // *-i
  }
  // stage d=1
#pragma unroll
  for (int base = 0; base < 8; base += 2) {
    float tr = xr[base] - xr[base + 1], ti = xi[base] - xi[base + 1];
    xr[base] += xr[base + 1]; xi[base] += xi[base + 1];
    xr[base + 1] = tr; xi[base + 1] = ti;
  }
  // mid twiddle: pos p holds k1=rev3[p]; *= cispi(-(l*k1)/256)
  REV3_INIT;
#pragma unroll
  for (int p = 1; p < 8; ++p) {
    float sn, cs;
    sincospif(-(float)(l * rev3[p]) * (1.0f / 256.0f), &sn, &cs);
    cmulf(xr[p], xi[p], cs, sn);
  }
  // 64-pt DIF across lanes (k2 ends bit-reversed in lane index)
#pragma unroll
  for (int st = 0; st < 6; ++st) {
    int d = 32 >> st;
    float sn, cs;
    sincospif(-(float)(l & (d - 1)) / (float)d, &sn, &cs);
    bool hi = (l & d) != 0;
#pragma unroll
    for (int p = 0; p < 8; ++p) {
      float vr = __shfl_xor(xr[p], d), vi = __shfl_xor(xi[p], d);
      float ar = hi ? vr - xr[p] : xr[p] + vr;
      float ai = hi ? vi - xi[p] : xi[p] + vi;
      float br = ar * cs - ai * sn, bi = ar * sn + ai * cs;
      xr[p] = hi ? br : ar;
      xi[p] = hi ? bi : ai;
    }
  }
}

__device__ __forceinline__ void wfft_inv(float* xr, float* xi, int l) {
  const float C = 0.70710678118654752f;
  // inverse 64-pt across lanes (reverse stages, conj twiddles, unnormalized)
#pragma unroll
  for (int st = 0; st < 6; ++st) {
    int d = 1 << st;
    float sn, cs;
    sincospif((float)(l & (d - 1)) / (float)d, &sn, &cs);
    bool hi = (l & d) != 0;
#pragma unroll
    for (int p = 0; p < 8; ++p) {
      float ar = xr[p], ai = xi[p];
      float mr = ar * cs - ai * sn, mi = ar * sn + ai * cs;
      float x2r = hi ? mr : ar, x2i = hi ? mi : ai;
      float vr = __shfl_xor(x2r, d), vi = __shfl_xor(x2i, d);
      xr[p] = hi ? vr - x2r : x2r + vr;
      xi[p] = hi ? vi - x2i : x2i + vi;
    }
  }
  // conj mid twiddle
  REV3_INIT;
#pragma unroll
  for (int p = 1; p < 8; ++p) {
    float sn, cs;
    sincospif((float)(l * rev3[p]) * (1.0f / 256.0f), &sn, &cs);
    cmulf(xr[p], xi[p], cs, sn);
  }
  // inverse 8-pt over regs: d=1
#pragma unroll
  for (int base = 0; base < 8; base += 2) {
    float ur = xr[base] + xr[base + 1], ui = xi[base] + xi[base + 1];
    float vr = xr[base] - xr[base + 1], vi = xi[base] - xi[base + 1];
    xr[base] = ur; xi[base] = ui; xr[base + 1] = vr; xi[base + 1] = vi;
  }
  // d=2 (conj twiddle +i on n=1)
#pragma unroll
  for (int h = 0; h < 8; h += 4) {
    { float or_ = xr[h + 2], oi = xi[h + 2];
      xr[h + 2] = xr[h] - or_; xi[h + 2] = xi[h] - oi;
      xr[h] += or_; xi[h] += oi; }
    { float or_ = -xi[h + 3], oi = xr[h + 3];                                 // *(+i)
      xr[h + 3] = xr[h + 1] - or_; xi[h + 3] = xi[h + 1] - oi;
      xr[h + 1] += or_; xi[h + 1] += oi; }
  }
  // d=4 (conj W8^n pre-mul on 5,6,7)
  { float a = xr[5], b = xi[5]; xr[5] = C * (a - b); xi[5] = C * (a + b); }   // *(C,+C)
  { float a = xr[6], b = xi[6]; xr[6] = -b; xi[6] = a; }                      // *(+i)
  { float a = xr[7], b = xi[7]; xr[7] = -C * (a + b); xi[7] = C * (a - b); }  // *(-C,+C)
#pragma unroll
  for (int n = 0; n < 4; ++n) {
    float or_ = xr[n + 4], oi = xi[n + 4];
    xr[n + 4] = xr[n] - or_; xi[n + 4] = xi[n] - oi;
    xr[n] += or_; xi[n] += oi;
  }
}

// ---------------------------------------------------------------------------
// Build P[u,m] = 256*d[m]*cis(+2pi kx A(u)),  Q[v,m] = cis(+2pi ky A(v))
// A(u) = u (u<256) else u-512.  f16, [pixel][m] layout for the GEMM.
// ---------------------------------------------------------------------------
__global__ __launch_bounds__(128) void ptq_build(
    const float* __restrict__ samples, const float* __restrict__ density,
    _Float16* __restrict__ Pr, _Float16* __restrict__ Pi2,
    _Float16* __restrict__ Qr, _Float16* __restrict__ Qi) {
  int m = blockIdx.x * 128 + threadIdx.x;
  int u = blockIdx.y;
  float A = (u < 256) ? (float)u : (float)(u - 512);
  float kx = samples[2 * m], ky = samples[2 * m + 1];
  float d = density[m] * 256.0f;
  float sx, cx, sy, cy;
  sincospif(2.0f * kx * A, &sx, &cx);
  sincospif(2.0f * ky * A, &sy, &cy);
  size_t o = (size_t)u * Mm + m;
  Pr[o] = (_Float16)(d * cx); Pi2[o] = (_Float16)(d * sx);
  Qr[o] = (_Float16)cy;       Qi[o] = (_Float16)sy;
}

// ---------------------------------------------------------------------------
// tc[u,v] = sum_m P[u,m]*Q[v,m]  (complex, f16 MFMA, K=1920) -> f32 float2
// 32x32x16 MFMA, tile 128u x 64v, 4 waves of 64u x 32v.
// ---------------------------------------------------------------------------
__global__ __launch_bounds__(256) void tc_gemm(
    const _Float16* __restrict__ Pr, const _Float16* __restrict__ Pi2,
    const _Float16* __restrict__ Qr, const _Float16* __restrict__ Qi,
    float2* __restrict__ tc) {
  __shared__ _Float16 sP[2 * 128 * 32];
  __shared__ _Float16 sQ[2 * 64 * 32];
  const int t = threadIdx.x;
  const int w = t >> 6, l = t & 63;
  const int lo = l & 31, hi = l >> 5;
  const int uw = (w & 1) * 64, vw = (w >> 1) * 32;
  const int u0 = blockIdx.x * 128, v0 = blockIdx.y * 64;

  const floatx16 z16 = {0.f,0.f,0.f,0.f,0.f,0.f,0.f,0.f,0.f,0.f,0.f,0.f,0.f,0.f,0.f,0.f};
  floatx16 accr[2] = {z16, z16}, acci[2] = {z16, z16};

  for (int mt = 0; mt < Mm / 32; ++mt) {
    const int m0 = mt * 32;
    __syncthreads();
#pragma unroll
    for (int pp = 0; pp < 2; ++pp) {
      int s = w * 2 + pp;
      int q = s * 64 + l;
      int r = q >> 2, cl = ((q & 3) - ((q >> 3) & 3)) & 3;
      int ga = (u0 + r) * Mm + m0 + cl * 8;
      gl_lds16(Pr + ga, &sP[s * 512]);
      gl_lds16(Pi2 + ga, &sP[4096 + s * 512]);
    }
    {
      int q = t;
      int r = q >> 2, cl = ((q & 3) - ((q >> 3) & 3)) & 3;
      int gb = (v0 + r) * Mm + m0 + cl * 8;
      gl_lds16(Qr + gb, &sQ[w * 512]);
      gl_lds16(Qi + gb, &sQ[2048 + w * 512]);
    }
    __syncthreads();
#pragma unroll
    for (int ks = 0; ks < 2; ++ks) {
      const int k = ks * 2 + hi;
      half8 ar[2], ai[2], nai[2], br, bi;
#pragma unroll
      for (int tm = 0; tm < 2; ++tm) {
        int rt = uw + tm * 32 + lo;
        int off = rt * 32 + (((rt >> 1) + k) & 3) * 8;
        ar[tm] = *(const half8*)&sP[off];
        ai[tm] = *(const half8*)&sP[4096 + off];
        nai[tm] = -ai[tm];
      }
      {
        int rt = vw + lo;
        int off = rt * 32 + (((rt >> 1) + k) & 3) * 8;
        br = *(const half8*)&sQ[off];
        bi = *(const half8*)&sQ[2048 + off];
      }
#pragma unroll
      for (int tm = 0; tm < 2; ++tm) {
        accr[tm] = __builtin_amdgcn_mfma_f32_32x32x16_f16(ar[tm],  br, accr[tm], 0, 0, 0);
        accr[tm] = __builtin_amdgcn_mfma_f32_32x32x16_f16(nai[tm], bi, accr[tm], 0, 0, 0);
        acci[tm] = __builtin_amdgcn_mfma_f32_32x32x16_f16(ar[tm],  bi, acci[tm], 0, 0, 0);
        acci[tm] = __builtin_amdgcn_mfma_f32_32x32x16_f16(ai[tm],  br, acci[tm], 0, 0, 0);
      }
    }
  }
#pragma unroll
  for (int tm = 0; tm < 2; ++tm)
#pragma unroll
    for (int reg = 0; reg < 16; ++reg) {
      int row = (reg & 3) + 8 * (reg >> 2) + 4 * hi;
      int u = u0 + uw + tm * 32 + row;
      int v = v0 + vw + lo;
      tc[(size_t)u * NF + v] = make_float2(accr[tm][reg], acci[tm][reg]);
    }
}

// ---------------------------------------------------------------------------
// T3: forward row-FFT of tc (512 full rows) -> Tr (slot order per row)
// ---------------------------------------------------------------------------
__global__ __launch_bounds__(256) void t3_rowfft(
    const float2* __restrict__ tc, float2* __restrict__ Tr) {
  int w = threadIdx.x >> 6, l = threadIdx.x & 63;
  int u = blockIdx.x * 4 + w;
  const float2* src = tc + (size_t)u * NF;
  float fr[8], fi[8];
#pragma unroll
  for (int s = 0; s < 8; ++s) { float2 v = src[s * 64 + l]; fr[s] = v.x; fi[s] = v.y; }
  wfft_fwd(fr, fi, l);
  REV3_INIT;
  float2* dst = Tr + (size_t)u * NF;
#pragma unroll
  for (int p = 0; p < 8; ++p) dst[rev3[p] * 64 + l] = make_float2(fr[p], fi[p]);
}

// ---------------------------------------------------------------------------
// T4: forward col-FFT of Tr -> That[p][q] (REAL, transposed store, scaled)
// Total scale: P carried 256*65536; want That = FFT2(t_true)*(65536/512^2)
//  => write factor = 65536/(512^2 * 256 * 65536) = 1/67108864
// ---------------------------------------------------------------------------
__global__ __launch_bounds__(256) void t4_colfft(
    const float2* __restrict__ Tr, float* __restrict__ That) {
  __shared__ float2 tile[64][17];
  int t = threadIdx.x, w = t >> 6, l = t & 63;
  int pt = blockIdx.x * 16;
  float fr[4][8], fi[4][8];
  for (int rc = 0; rc < 8; ++rc) {
    __syncthreads();
    int rr = t >> 2, q = t & 3;
    const float2* g = Tr + (size_t)(rc * 64 + rr) * NF + pt + q * 4;
    float4 v0 = *(const float4*)g;
    float4 v1 = *(const float4*)(g + 2);
    tile[rr][q * 4 + 0] = make_float2(v0.x, v0.y);
    tile[rr][q * 4 + 1] = make_float2(v0.z, v0.w);
    tile[rr][q * 4 + 2] = make_float2(v1.x, v1.y);
    tile[rr][q * 4 + 3] = make_float2(v1.z, v1.w);
    __syncthreads();
#pragma unroll
    for (int pi = 0; pi < 4; ++pi) {
      float2 e = tile[l][w * 4 + pi];
      fr[pi][rc] = e.x; fi[pi][rc] = e.y;
    }
  }
  REV3_INIT;
  const float sc = 1.0f / 67108864.0f;
#pragma unroll
  for (int pi = 0; pi < 4; ++pi) {
    wfft_fwd(fr[pi], fi[pi], l);
    int p = pt + w * 4 + pi;
#pragma unroll
    for (int q8 = 0; q8 < 8; ++q8)
      That[(size_t)p * NF + rev3[q8] * 64 + l] = fr[pi][q8] * sc;
  }
}

// ---------------------------------------------------------------------------
// K1: per (b, image row r<256): zero-pad to 512, forward FFT, store f16 W1
// ---------------------------------------------------------------------------
__global__ __launch_bounds__(256) void k1_rowfft(
    const float* __restrict__ xr, const float* __restrict__ xi,
    __half2* __restrict__ W1, int bbase) {
  int w = threadIdx.x >> 6, l = threadIdx.x & 63;
  int r = blockIdx.x * 4 + w;
  int bl = blockIdx.y;
  int b = bbase + bl;
  const float* pr = xr + ((size_t)b * IMG + r) * IMG;
  const float* pim = xi + ((size_t)b * IMG + r) * IMG;
  float fr[8], fi[8];
#pragma unroll
  for (int s = 0; s < 4; ++s) { fr[s] = pr[s * 64 + l]; fi[s] = pim[s * 64 + l]; }
#pragma unroll
  for (int s = 4; s < 8; ++s) { fr[s] = 0.f; fi[s] = 0.f; }
  wfft_fwd(fr, fi, l);
  REV3_INIT;
  __half2* dst = W1 + ((size_t)bl * IMG + r) * NF;
#pragma unroll
  for (int p = 0; p < 8; ++p)
    dst[rev3[p] * 64 + l] = __floats2half2_rn(fr[p], fi[p]);
}

// ---------------------------------------------------------------------------
// K2: per (b, 16 stored-cols): col fwd-FFT (rows<256 nonzero), .*That,
// col inv-FFT, store rows<256 back IN-PLACE. 4 waves x 4 cols each.
// ---------------------------------------------------------------------------
__global__ __launch_bounds__(256) void k2_colpass(
    __half2* __restrict__ W1, const float* __restrict__ That) {
  __shared__ __half2 tile[64][17];
  int t = threadIdx.x, w = t >> 6, l = t & 63;
  int pt = blockIdx.x * 16;
  int bl = blockIdx.y;
  float fr[4][8], fi[4][8];
  for (int rc = 0; rc < 4; ++rc) {
    __syncthreads();
    int rr = t >> 2, q = t & 3;
    const __half2* g = W1 + ((size_t)bl * IMG + rc * 64 + rr) * NF + pt + q * 4;
    float4 v = *(const float4*)g;
    __half2 hh[4];
    *(float4*)hh = v;
    tile[rr][q * 4 + 0] = hh[0];
    tile[rr][q * 4 + 1] = hh[1];
    tile[rr][q * 4 + 2] = hh[2];
    tile[rr][q * 4 + 3] = hh[3];
    __syncthreads();
#pragma unroll
    for (int pi = 0; pi < 4; ++pi) {
      float2 e = __half22float2(tile[l][w * 4 + pi]);
      fr[pi][rc] = e.x; fi[pi][rc] = e.y;
    }
  }
#pragma unroll
  for (int pi = 0; pi < 4; ++pi)
#pragma unroll
    for (int s = 4; s < 8; ++s) { fr[pi][s] = 0.f; fi[pi][s] = 0.f; }
  REV3_INIT;
#pragma unroll
  for (int pi = 0; pi < 4; ++pi) {
    wfft_fwd(fr[pi], fi[pi], l);
    int p = pt + w * 4 + pi;
#pragma unroll
    for (int q8 = 0; q8 < 8; ++q8) {
      float T = That[(size_t)p * NF + rev3[q8] * 64 + l];
      fr[pi][q8] *= T; fi[pi][q8] *= T;
    }
    wfft_inv(fr[pi], fi[pi], l);
  }
  for (int rc = 0; rc < 4; ++rc) {
    __syncthreads();
#pragma unroll
    for (int pi = 0; pi < 4; ++pi)
      tile[l][w * 4 + pi] = __floats2half2_rn(fr[pi][rc], fi[pi][rc]);
    __syncthreads();
    int rr = t >> 2, q = t & 3;
    __half2 hh[4];
    hh[0] = tile[rr][q * 4 + 0];
    hh[1] = tile[rr][q * 4 + 1];
    hh[2] = tile[rr][q * 4 + 2];
    hh[3] = tile[rr][q * 4 + 3];
    __half2* g = W1 + ((size_t)bl * IMG + rc * 64 + rr) * NF + pt + q * 4;
    *(float4*)g = *(float4*)hh;
  }
}

// ---------------------------------------------------------------------------
// K3: per (b, row r<256): inverse row-FFT, crop cols<256, scale 2^-16, write
// interleaved re/im f32 output.
// ---------------------------------------------------------------------------
__global__ __launch_bounds__(256) void k3_rowifft(
    const __half2* __restrict__ W1, float* __restrict__ out, int bbase) {
  int w = threadIdx.x >> 6, l = threadIdx.x & 63;
  int r = blockIdx.x * 4 + w;
  int bl = blockIdx.y;
  int b = bbase + bl;
  const __half2* src = W1 + ((size_t)bl * IMG + r) * NF;
  REV3_INIT;
  float fr[8], fi[8];
#pragma unroll
  for (int p = 0; p < 8; ++p) {
    float2 v = __half22float2(src[rev3[p] * 64 + l]);
    fr[p] = v.x; fi[p] = v.y;
  }
  wfft_inv(fr, fi, l);
  const float sc = 1.0f / 65536.0f;
  float2* dst = (float2*)(out + ((size_t)b * IMG + r) * IMG * 2);
#pragma unroll
  for (int s = 0; s < 4; ++s)
    dst[s * 64 + l] = make_float2(fr[s] * sc, fi[s] * sc);
}

// ---------------------------------------------------------------------------
// Launch
// ---------------------------------------------------------------------------
extern "C" void kernel_launch(void* const* d_in, const int* in_sizes, int n_in,
                              void* d_out, int out_size, void* d_ws, size_t ws_size,
                              hipStream_t stream) {
  (void)in_sizes; (void)n_in; (void)out_size; (void)ws_size;

  const float* xr      = (const float*)d_in[0];
  const float* xi      = (const float*)d_in[1];
  const float* samples = (const float*)d_in[2];
  const float* density = (const float*)d_in[3];
  float* out = (float*)d_out;

  // Workspace layout (bytes):
  char* ws = (char*)d_ws;
  _Float16* Pr  = (_Float16*)(ws + 0);                  // 512*1920 f16 = 1.97 MB
  _Float16* Pi2 = (_Float16*)(ws + 1966080);
  _Float16* Qr  = (_Float16*)(ws + 3932160);
  _Float16* Qi  = (_Float16*)(ws + 5898240);
  float2*   tc  = (float2*)(ws + 7864320);              // 512*512 float2 = 2 MB
  float2*   Tr  = (float2*)(ws + 7864320 + 2097152);
  float*    That= (float*)(ws + 7864320 + 2 * 2097152); // 512*512 f32 = 1 MB
  __half2*  W1  = (__half2*)(ws + 7864320 + 2 * 2097152 + 1048576); // 32*256*512 half2 = 16 MB
  // total ~= 29 MB

  // --- one-time (per launch) Toeplitz kernel build ---
  ptq_build<<<dim3(Mm / 128, NF), 128, 0, stream>>>(samples, density, Pr, Pi2, Qr, Qi);
  tc_gemm<<<dim3(NF / 128, NF / 64), 256, 0, stream>>>(Pr, Pi2, Qr, Qi, tc);
  t3_rowfft<<<dim3(NF / 4), 256, 0, stream>>>(tc, Tr);
  t4_colfft<<<dim3(NF / 16), 256, 0, stream>>>(Tr, That);

  // --- main pipeline, two batch halves sharing W1 ---
  for (int h = 0; h < 2; ++h) {
    int bbase = h * BH;
    k1_rowfft<<<dim3(IMG / 4, BH), 256, 0, stream>>>(xr, xi, W1, bbase);
    k2_colpass<<<dim3(NF / 16, BH), 256, 0, stream>>>(W1, That);
    k3_rowifft<<<dim3(IMG / 4, BH), 256, 0, stream>>>(W1, out, bbase);
  }
}